// Round 13
// baseline (665.444 us; speedup 1.0000x reference)
//
#include <hip/hip_runtime.h>
#include <math.h>

#define T_TOKENS 16384
#define HID      4096
#define NEXP     256
#define NGROUP   8
#define GSIZE    32
#define TOPKG    4
#define TOPK     8
#define RSCALE   2.5f

#define TAU   1.5e-5f    // expert-score margin (9 sigma at sigma~1.7e-6)
#define TAUG  2.5e-5f    // group-score margin  (10 sigma at sqrt(2)*sigma)

// ---- split-K GEMM config (R9-validated) ----
#define BM     64
#define BK     32
#define SPLITK 4
#define KSPAN  (HID / SPLITK)    // 1024
#define NKS    (KSPAN / BK)      // 32 K-steps per block
#define NSG    (HID / BK)        // 128 global K-steps
#define NMT    (T_TOKENS / BM)   // 256 m-tiles

// LDS staging (ushort units), UNPADDED frag-major (R9-validated):
//   elem(r,k) = (r>>4)*512 + ((k&31)>>3)*128 + (r&15)*8 + (k&7)
#define A_HI   0
#define A_LO   2048
#define B_HI   4096
#define B_LO   12288
#define STG_TOT 20480            // ushorts = 40 KB -> 4 blocks/CU
#define FLAG_U16 20476           // flag int at bytes 40952..40955 (above 32KB Lg)

// converted-weight limb size (ushorts): 128 steps x 8192
#define WQ_LIMB (NSG * 8192)

typedef __attribute__((ext_vector_type(8))) short bf16x8;
typedef __attribute__((ext_vector_type(4))) float f32x4;

__device__ __forceinline__ int stoffA(int r, int q) {
    return (r >> 4) * 512 + (q >> 1) * 128 + (r & 15) * 8 + (q & 1) * 4;
}
__device__ __forceinline__ int froffL(int lane) {
    return (lane >> 4) * 128 + (lane & 15) * 8;
}

// async global->LDS, 16 B per lane (R9-validated)
__device__ __forceinline__ void gload16(const void* g, void* l) {
    __builtin_amdgcn_global_load_lds(
        (const __attribute__((address_space(1))) void*)g,
        (__attribute__((address_space(3))) void*)l, 16, 0, 0);
}

// Split float4 into packed bf16 hi (RNE) and lo (RNE of exact residual).
__device__ __forceinline__ void split4(const float4 v, uint& h01, uint& h23,
                                       uint& l01, uint& l23) {
    const uint u0 = __float_as_uint(v.x) + 0x8000u;
    const uint u1 = __float_as_uint(v.y) + 0x8000u;
    const uint u2 = __float_as_uint(v.z) + 0x8000u;
    const uint u3 = __float_as_uint(v.w) + 0x8000u;
    h01 = __builtin_amdgcn_perm(u1, u0, 0x07060302u);
    h23 = __builtin_amdgcn_perm(u3, u2, 0x07060302u);
    const float f0 = v.x - __uint_as_float(u0 & 0xFFFF0000u);
    const float f1 = v.y - __uint_as_float(u1 & 0xFFFF0000u);
    const float f2 = v.z - __uint_as_float(u2 & 0xFFFF0000u);
    const float f3 = v.w - __uint_as_float(u3 & 0xFFFF0000u);
    l01 = __builtin_amdgcn_perm(__float_as_uint(f1) + 0x8000u,
                                __float_as_uint(f0) + 0x8000u, 0x07060302u);
    l23 = __builtin_amdgcn_perm(__float_as_uint(f3) + 0x8000u,
                                __float_as_uint(f2) + 0x8000u, 0x07060302u);
}

// ---- shared routing decision (identical in all paths; validated R5-R12) ----
template <class SC>
__device__ __forceinline__ bool route_core(SC sc, const float* __restrict__ bias,
                                           int* id, float* wv)
{
    float gs[NGROUP];
#pragma unroll
    for (int g = 0; g < NGROUP; ++g) {
        float m1 = -1e30f, m2 = -1e30f;
        for (int i = 0; i < GSIZE; ++i) {
            const int e = g * GSIZE + i;
            const float v = sc(e) + bias[e];
            if (v > m1)      { m2 = m1; m1 = v; }
            else if (v > m2) { m2 = v; }
        }
        gs[g] = m1 + m2;
    }

    unsigned gmask = 0;
    float g4 = -1e30f;
#pragma unroll
    for (int r = 0; r < TOPKG; ++r) {
        int bi = 0; float bv = -1e30f;
#pragma unroll
        for (int g = 0; g < NGROUP; ++g) {
            const bool taken = (gmask >> g) & 1;
            if (!taken && gs[g] > bv) { bv = gs[g]; bi = g; }
        }
        gmask |= 1u << bi;
        g4 = bv;
    }
    float g5 = -1e30f;
#pragma unroll
    for (int g = 0; g < NGROUP; ++g)
        if (!((gmask >> g) & 1) && gs[g] > g5) g5 = gs[g];

    float val[TOPK + 1]; int vid[TOPK + 1];
#pragma unroll
    for (int r = 0; r <= TOPK; ++r) { val[r] = -1e30f; vid[r] = 0; }
    for (int e = 0; e < NEXP; ++e) {
        const bool allowed = (gmask >> (e >> 5)) & 1;
        const float v = allowed ? (sc(e) + bias[e]) : 0.0f;
        if (v > val[TOPK]) {
#pragma unroll
            for (int p = TOPK; p >= 1; --p) {
                if (v > val[p - 1])  { val[p] = val[p - 1]; vid[p] = vid[p - 1]; }
                else if (v > val[p]) { val[p] = v;          vid[p] = e; }
            }
            if (v > val[0]) { val[0] = v; vid[0] = e; }
        }
    }

    bool tight = (g4 - g5 < TAUG);
#pragma unroll
    for (int i = 0; i < TOPK; ++i) tight |= (val[i] - val[i + 1] < TAU);

    float sum = 0.0f;
#pragma unroll
    for (int r = 0; r < TOPK; ++r) { id[r] = vid[r]; wv[r] = sc(vid[r]); sum += wv[r]; }
    const float inv = RSCALE / (sum + 1e-20f);
#pragma unroll
    for (int r = 0; r < TOPK; ++r) wv[r] *= inv;
    return tight;
}

// exact fp32 recompute + route for one token (cold fallback only)
__device__ void exact_token(const float* __restrict__ hs, const float* __restrict__ wt,
                            const float* __restrict__ bias, float* __restrict__ out, int t)
{
    float lg[NEXP];
    const float* hrow = hs + (size_t)t * HID;
    for (int e = 0; e < NEXP; ++e) {
        const float* wr = wt + (size_t)e * HID;
        float a = 0.0f;
        for (int k = 0; k < HID; k += 4) {
            const float4 x = *(const float4*)(hrow + k);
            const float4 b = *(const float4*)(wr + k);
            a = fmaf(x.x, b.x, a); a = fmaf(x.y, b.y, a);
            a = fmaf(x.z, b.z, a); a = fmaf(x.w, b.w, a);
        }
        lg[e] = 1.0f / (1.0f + expf(-a));
    }
    int id[TOPK]; float wv[TOPK];
    route_core([&](int e) { return lg[e]; }, bias, id, wv);
    for (int r = 0; r < TOPK; ++r) {
        out[(size_t)t * TOPK + r] = (float)id[r];
        out[(size_t)T_TOKENS * TOPK + (size_t)t * TOPK + r] = wv[r];
    }
}

// =============== one-shot weight conversion (R9-validated, unchanged) ===============
__global__ __launch_bounds__(256, 8)
void conv_weight(const float* __restrict__ wt, ushort* __restrict__ wq)
{
    const int g  = blockIdx.x * 256 + threadIdx.x;
    const int e  = g >> 9;
    const int kc = g & 511;
    const int sg  = kc >> 2;
    const int kch = kc & 3;

    const float4 v0 = *(const float4*)(wt + (size_t)e * HID + kc * 8);
    const float4 v1 = *(const float4*)(wt + (size_t)e * HID + kc * 8 + 4);
    uint h01, h23, l01, l23, h45, h67, l45, l67;
    split4(v0, h01, h23, l01, l23);
    split4(v1, h45, h67, l45, l67);

    const size_t idx = (size_t)sg * 8192 + (size_t)((e >> 4) * 512 + kch * 128 + (e & 15) * 8);
    uint4 hv; hv.x = h01; hv.y = h23; hv.z = h45; hv.w = h67;
    uint4 lv; lv.x = l01; lv.y = l23; lv.z = l45; lv.w = l67;
    *(uint4*)&wq[idx] = hv;
    *(uint4*)&wq[(size_t)WQ_LIMB + idx] = lv;
}

// =============== split-K GEMM v2 (R9-verbatim loop) + fused last-block route ===============
__global__ __launch_bounds__(256, 4)
void router_gemm(const float* __restrict__ hs, const ushort* __restrict__ wq,
                 const float* __restrict__ bias,
                 float* __restrict__ pw, float* __restrict__ out,
                 unsigned* __restrict__ cntm,
                 unsigned* __restrict__ wcnt, unsigned* __restrict__ wlist, unsigned cap)
{
    __shared__ ushort u16[STG_TOT];

    const int tid  = threadIdx.x;
    const int lane = tid & 63;
    const int w    = tid >> 6;
    const int m    = blockIdx.x >> 2;
    const int sk   = blockIdx.x & 3;
    const int t0   = m * BM;
    const int kb0  = sk * KSPAN;
    const int r0   = tid >> 3;           // 0..31
    const int q    = tid & 7;

    const ushort* wq_hi = wq;
    const ushort* wq_lo = wq + WQ_LIMB;

    f32x4 acc[4][4];
#pragma unroll
    for (int i = 0; i < 4; ++i)
#pragma unroll
        for (int j = 0; j < 4; ++j) acc[i][j] = (f32x4)0.0f;

    float4 ra[2];
#pragma unroll
    for (int s = 0; s < 2; ++s)
        ra[s] = *(const float4*)(hs + (size_t)(t0 + r0 + 32 * s) * HID + kb0 + q * 4);

    for (int ks = 0; ks < NKS; ++ks) {
        const int sg = sk * NKS + ks;
        __syncthreads();   // previous compute done; LDS reusable

        // ---- B: DMA pre-converted tiles (wave w stages its quarter) ----
        {
            const size_t gb = (size_t)sg * 8192 + (size_t)(w * 4) * 512 + (size_t)lane * 8;
#pragma unroll
            for (int i = 0; i < 4; ++i) {
                gload16(wq_hi + gb + i * 512, &u16[B_HI + (w * 4 + i) * 512]);
                gload16(wq_lo + gb + i * 512, &u16[B_LO + (w * 4 + i) * 512]);
            }
        }
        // ---- A: convert regs -> bf16 hi/lo, write frag-major LDS ----
#pragma unroll
        for (int s = 0; s < 2; ++s) {
            const int r = r0 + 32 * s;
            uint h01, h23, l01, l23;
            split4(ra[s], h01, h23, l01, l23);
            const int eo = stoffA(r, q);
            uint2 hv; hv.x = h01; hv.y = h23;
            uint2 lv; lv.x = l01; lv.y = l23;
            *(uint2*)&u16[A_HI + eo] = hv;
            *(uint2*)&u16[A_LO + eo] = lv;
        }
        __syncthreads();   // drains B DMA (vmcnt) + A writes visible

        // ---- prefetch next A K-step into regs ----
        if (ks + 1 < NKS) {
            const int kb = kb0 + (ks + 1) * BK;
#pragma unroll
            for (int s = 0; s < 2; ++s)
                ra[s] = *(const float4*)(hs + (size_t)(t0 + r0 + 32 * s) * HID + kb + q * 4);
        }

        // ---- compute: linear b128 frag reads (bank floor) + 48 MFMA/wave ----
        const int fo = froffL(lane);
        bf16x8 ah[4], al[4];
#pragma unroll
        for (int rt = 0; rt < 4; ++rt) {
            ah[rt] = *(const bf16x8*)&u16[A_HI + rt * 512 + fo];
            al[rt] = *(const bf16x8*)&u16[A_LO + rt * 512 + fo];
        }
#pragma unroll
        for (int c = 0; c < 4; ++c) {
            const int ct = w * 4 + c;
            const bf16x8 bh = *(const bf16x8*)&u16[B_HI + ct * 512 + fo];
            const bf16x8 bl = *(const bf16x8*)&u16[B_LO + ct * 512 + fo];
#pragma unroll
            for (int rt = 0; rt < 4; ++rt) {
                acc[rt][c] = __builtin_amdgcn_mfma_f32_16x16x32_bf16(ah[rt], bh, acc[rt][c], 0, 0, 0);
                acc[rt][c] = __builtin_amdgcn_mfma_f32_16x16x32_bf16(ah[rt], bl, acc[rt][c], 0, 0, 0);
                acc[rt][c] = __builtin_amdgcn_mfma_f32_16x16x32_bf16(al[rt], bh, acc[rt][c], 0, 0, 0);
            }
        }
    }

    // ---- store raw partial logits: pw[sk][token][expert] ----
#pragma unroll
    for (int rt = 0; rt < 4; ++rt)
#pragma unroll
        for (int c = 0; c < 4; ++c) {
            const int col  = w * 64 + c * 16 + (lane & 15);
            const int rowb = rt * 16 + (lane >> 4) * 4;
#pragma unroll
            for (int j = 0; j < 4; ++j)
                pw[((size_t)(sk * T_TOKENS) + t0 + rowb + j) * NEXP + col] = acc[rt][c][j];
        }

    // ---- fused split-K completion (R10-validated pattern, SPLITK=4) ----
    __threadfence();                      // release: publish pw stores
    __syncthreads();                      // all threads' stores+fences done
    volatile int* flag = (volatile int*)&u16[FLAG_U16];
    if (tid == 0) {
        const unsigned old = atomicAdd(&cntm[m], 1u);
        *flag = (old == SPLITK - 1) ? 1 : 0;
    }
    __syncthreads();
    if (*flag) {
        __threadfence();                  // acquire: peer slices visible
        float* Lg = (float*)u16;          // 32 KB half-buffer (staging dead)
#pragma unroll
        for (int h = 0; h < 2; ++h) {     // two 32-token halves
            __syncthreads();              // guard Lg reuse (h=1)
            // sum partials FIXED order s=0..3 (deterministic) -> sigmoid -> swizzled Lg
#pragma unroll 8
            for (int t = 0; t < 32; ++t) {
                const int row = t0 + h * 32 + t;
                float v = 0.0f;
#pragma unroll
                for (int s = 0; s < SPLITK; ++s)
                    v += pw[((size_t)(s * T_TOKENS) + row) * NEXP + tid];
                Lg[tid * 32 + ((t + tid) & 31)] = 1.0f / (1.0f + expf(-v));
            }
            __syncthreads();

            if (tid < 32) {
                const int t = t0 + h * 32 + tid;
                int id[TOPK]; float wv[TOPK];
                const bool tight = route_core(
                    [&](int e) { return Lg[e * 32 + ((tid + e) & 31)]; }, bias, id, wv);
#pragma unroll
                for (int r = 0; r < TOPK; ++r) {
                    out[(size_t)t * TOPK + r] = (float)id[r];
                    out[(size_t)T_TOKENS * TOPK + (size_t)t * TOPK + r] = wv[r];
                }
                if (tight) {
                    const unsigned pos = atomicAdd(wcnt, 1u);
                    if (pos < cap) wlist[pos] = (unsigned)t;
                }
            }
        }
    }
}

// =============== cleanup v3 (R8-verbatim): one token per block, deep-issue ===============
__global__ __launch_bounds__(256, 4)
void router_exact(const float* __restrict__ hs, const float* __restrict__ wt,
                  const float* __restrict__ bias, float* __restrict__ out,
                  const unsigned* __restrict__ wcnt, const unsigned* __restrict__ wlist,
                  unsigned cap)
{
    __shared__ float hrow[HID];          // 16 KB
    __shared__ float lg[NEXP];           // 1 KB
    const unsigned count = min(*wcnt, cap);
    const int tid  = threadIdx.x;
    const int lane = tid & 63;
    const int w    = tid >> 6;

    for (unsigned b = blockIdx.x; b < count; b += gridDim.x) {
        __syncthreads();                 // guard hrow/lg reuse across passes
        const int t = (int)wlist[b];

#pragma unroll
        for (int i = 0; i < 4; ++i) {
            const int f4 = i * 256 + tid;
            *(float4*)&hrow[f4 * 4] = *(const float4*)(hs + (size_t)t * HID + f4 * 4);
        }
        __syncthreads();

        for (int g = 0; g < 16; ++g) {
            const int e0 = w * 64 + g * 4;
            float a[4] = {0.0f, 0.0f, 0.0f, 0.0f};
#pragma unroll 4
            for (int j = 0; j < 16; ++j) {
                const int f4 = j * 64 + lane;
                const float4 h = *(const float4*)&hrow[f4 * 4];
#pragma unroll
                for (int p = 0; p < 4; ++p) {
                    const float4 v = *(const float4*)(wt + (size_t)(e0 + p) * HID + f4 * 4);
                    a[p] = fmaf(h.x, v.x, a[p]); a[p] = fmaf(h.y, v.y, a[p]);
                    a[p] = fmaf(h.z, v.z, a[p]); a[p] = fmaf(h.w, v.w, a[p]);
                }
            }
#pragma unroll
            for (int p = 0; p < 4; ++p)
#pragma unroll
                for (int d = 1; d < 64; d <<= 1)
                    a[p] += __shfl_xor(a[p], d, 64);
            if (lane == 0) {
#pragma unroll
                for (int p = 0; p < 4; ++p)
                    lg[e0 + p] = 1.0f / (1.0f + expf(-a[p]));
            }
        }
        __syncthreads();

        if (tid == 0) {
            int id[TOPK]; float wv[TOPK];
            route_core([&](int e) { return lg[e]; }, bias, id, wv);
            for (int r = 0; r < TOPK; ++r) {
                out[(size_t)t * TOPK + r] = (float)id[r];
                out[(size_t)T_TOKENS * TOPK + (size_t)t * TOPK + r] = wv[r];
            }
        }
    }
}

// =============== fallback monolith (R5-validated, unchanged) ===============
__global__ __launch_bounds__(512, 1)
void router_mono(const float* __restrict__ hs, const float* __restrict__ wt,
                 const float* __restrict__ bias, float* __restrict__ out,
                 unsigned* __restrict__ wcnt, unsigned* __restrict__ wlist, unsigned cap)
{
    __shared__ float smem[16384];
    ushort* u16 = (ushort*)smem;
    float*  Lg  = smem;

    const int tid  = threadIdx.x;
    const int lane = tid & 63;
    const int w    = tid >> 6;
    const int t0   = blockIdx.x * 64;
    const int ar   = tid >> 3;
    const int aq   = tid & 7;

    f32x4 acc[4][2];
#pragma unroll
    for (int i = 0; i < 4; ++i)
#pragma unroll
        for (int j = 0; j < 2; ++j) acc[i][j] = (f32x4)0.0f;

    float4 ra, rb[4];
    ra = *(const float4*)(hs + (size_t)(t0 + ar) * HID + aq * 4);
#pragma unroll
    for (int s = 0; s < 4; ++s)
        rb[s] = *(const float4*)(wt + (size_t)(ar + s * 64) * HID + aq * 4);

    for (int ks = 0; ks < HID / BK; ++ks) {
        __syncthreads();
        {
            uint h01, h23, l01, l23;
            split4(ra, h01, h23, l01, l23);
            const int eo = stoffA(ar, aq);
            uint2 hv; hv.x = h01; hv.y = h23;
            uint2 lv; lv.x = l01; lv.y = l23;
            *(uint2*)&u16[0 + eo] = hv;
            *(uint2*)&u16[2048 + eo] = lv;
        }
#pragma unroll
        for (int s = 0; s < 4; ++s) {
            const int e = ar + s * 64;
            uint h01, h23, l01, l23;
            split4(rb[s], h01, h23, l01, l23);
            const int eo = stoffA(e, aq);
            uint2 hv; hv.x = h01; hv.y = h23;
            uint2 lv; lv.x = l01; lv.y = l23;
            *(uint2*)&u16[4096 + eo] = hv;
            *(uint2*)&u16[12288 + eo] = lv;
        }
        __syncthreads();
        if (ks + 1 < HID / BK) {
            const int k0 = (ks + 1) * BK;
            ra = *(const float4*)(hs + (size_t)(t0 + ar) * HID + k0 + aq * 4);
#pragma unroll
            for (int s = 0; s < 4; ++s)
                rb[s] = *(const float4*)(wt + (size_t)(ar + s * 64) * HID + k0 + aq * 4);
        }
        const int fo = froffL(lane);
        bf16x8 ah[4], al[4];
#pragma unroll
        for (int rt = 0; rt < 4; ++rt) {
            ah[rt] = *(const bf16x8*)&u16[0 + rt * 512 + fo];
            al[rt] = *(const bf16x8*)&u16[2048 + rt * 512 + fo];
        }
#pragma unroll
        for (int c = 0; c < 2; ++c) {
            const int ct = w * 2 + c;
            const bf16x8 bh = *(const bf16x8*)&u16[4096 + ct * 512 + fo];
            const bf16x8 bl = *(const bf16x8*)&u16[12288 + ct * 512 + fo];
#pragma unroll
            for (int rt = 0; rt < 4; ++rt) {
                acc[rt][c] = __builtin_amdgcn_mfma_f32_16x16x32_bf16(ah[rt], bh, acc[rt][c], 0, 0, 0);
                acc[rt][c] = __builtin_amdgcn_mfma_f32_16x16x32_bf16(ah[rt], bl, acc[rt][c], 0, 0, 0);
                acc[rt][c] = __builtin_amdgcn_mfma_f32_16x16x32_bf16(al[rt], bh, acc[rt][c], 0, 0, 0);
            }
        }
    }
    __syncthreads();
#pragma unroll
    for (int rt = 0; rt < 4; ++rt)
#pragma unroll
        for (int c = 0; c < 2; ++c) {
            const int col  = w * 32 + c * 16 + (lane & 15);
            const int rowb = rt * 16 + (lane >> 4) * 4;
#pragma unroll
            for (int j = 0; j < 4; ++j) {
                const int row = rowb + j;
                Lg[col * 64 + ((row + col) & 63)] = 1.0f / (1.0f + expf(-acc[rt][c][j]));
            }
        }
    __syncthreads();

    if (tid < 64) {
        const int t = t0 + tid;
        int id[TOPK]; float wv[TOPK];
        const bool tight = route_core(
            [&](int e) { return Lg[e * 64 + ((tid + e) & 63)]; }, bias, id, wv);
#pragma unroll
        for (int r = 0; r < TOPK; ++r) {
            out[(size_t)t * TOPK + r] = (float)id[r];
            out[(size_t)T_TOKENS * TOPK + (size_t)t * TOPK + r] = wv[r];
        }
        if (tight) {
            bool queued = false;
            if (wcnt) {
                const unsigned pos = atomicAdd(wcnt, 1u);
                if (pos < cap) { wlist[pos] = (unsigned)t; queued = true; }
            }
            if (!queued) exact_token(hs, wt, bias, out, t);
        }
    }
}

extern "C" void kernel_launch(void* const* d_in, const int* in_sizes, int n_in,
                              void* d_out, int out_size, void* d_ws, size_t ws_size,
                              hipStream_t stream) {
    const float* hs   = (const float*)d_in[0];   // [16384, 4096] f32
    const float* wt   = (const float*)d_in[1];   // [256, 4096]   f32
    const float* bias = (const float*)d_in[2];   // [256]         f32
    float* out = (float*)d_out;
    (void)in_sizes; (void)n_in; (void)out_size;

    const size_t PW_BYTES  = (size_t)SPLITK * T_TOKENS * NEXP * 4;  // 64 MB
    const size_t WQ_BYTES  = (size_t)2 * WQ_LIMB * 2;               // 4 MB
    const size_t CTL_BYTES = 4 + (size_t)NMT * 4;                   // wcnt + cntm
    const size_t NEED = PW_BYTES + WQ_BYTES + CTL_BYTES + (size_t)T_TOKENS * 4;

    if (ws_size >= NEED) {
        float*    pw    = (float*)d_ws;
        ushort*   wq    = (ushort*)((char*)d_ws + PW_BYTES);
        unsigned* wcnt  = (unsigned*)((char*)d_ws + PW_BYTES + WQ_BYTES);
        unsigned* cntm  = wcnt + 1;                  // [NMT]
        unsigned* wlist = cntm + NMT;
        hipMemsetAsync(wcnt, 0, CTL_BYTES, stream);  // zero wcnt + cntm each call
        conv_weight<<<512, 256, 0, stream>>>(wt, wq);
        router_gemm<<<NMT * SPLITK, 256, 0, stream>>>(hs, wq, bias, pw, out,
                                                      cntm, wcnt, wlist,
                                                      (unsigned)T_TOKENS);
        router_exact<<<2048, 256, 0, stream>>>(hs, wt, bias, out, wcnt, wlist,
                                               (unsigned)T_TOKENS);
    } else if (ws_size >= 8) {
        unsigned cap = (unsigned)((ws_size - 4) / 4);
        if (cap > T_TOKENS) cap = T_TOKENS;
        unsigned* wcnt  = (unsigned*)d_ws;
        unsigned* wlist = wcnt + 1;
        hipMemsetAsync(d_ws, 0, sizeof(unsigned), stream);
        router_mono<<<T_TOKENS / 64, 512, 0, stream>>>(hs, wt, bias, out, wcnt, wlist, cap);
        router_exact<<<2048, 256, 0, stream>>>(hs, wt, bias, out, wcnt, wlist, cap);
    } else {
        router_mono<<<T_TOKENS / 64, 512, 0, stream>>>(hs, wt, bias, out,
                                                       nullptr, nullptr, 0u);
    }
}

// Round 14
// 336.693 us; speedup vs baseline: 1.9764x; 1.9764x over previous
//
#include <hip/hip_runtime.h>
#include <math.h>

#define T_TOKENS 16384
#define HID      4096
#define NEXP     256
#define NGROUP   8
#define GSIZE    32
#define TOPKG    4
#define TOPK     8
#define RSCALE   2.5f

#define TAU   1.5e-5f    // expert-score margin (R13-validated)
#define TAUG  2.5e-5f    // group-score margin  (R13-validated)

// ---- split-K GEMM config (R9-validated) ----
#define BM     64
#define BK     32
#define SPLITK 4
#define KSPAN  (HID / SPLITK)    // 1024
#define NKS    (KSPAN / BK)      // 32 K-steps per block
#define NSG    (HID / BK)        // 128 global K-steps

// LDS staging (ushort units), UNPADDED frag-major (R9-validated):
//   elem(r,k) = (r>>4)*512 + ((k&31)>>3)*128 + (r&15)*8 + (k&7)
#define A_HI   0
#define A_LO   2048
#define B_HI   4096
#define B_LO   12288
#define STG_TOT 20480            // ushorts = 40 KB -> 4 blocks/CU

// converted-weight limb size (ushorts): 128 steps x 8192
#define WQ_LIMB (NSG * 8192)

#define RT_TOK 16                // route tokens/block -> grid 1024, 4 blocks/CU

typedef __attribute__((ext_vector_type(8))) short bf16x8;
typedef __attribute__((ext_vector_type(4))) float f32x4;

__device__ __forceinline__ int stoffA(int r, int q) {
    return (r >> 4) * 512 + (q >> 1) * 128 + (r & 15) * 8 + (q & 1) * 4;
}
__device__ __forceinline__ int froffL(int lane) {
    return (lane >> 4) * 128 + (lane & 15) * 8;
}

// async global->LDS, 16 B per lane (R9-validated)
__device__ __forceinline__ void gload16(const void* g, void* l) {
    __builtin_amdgcn_global_load_lds(
        (const __attribute__((address_space(1))) void*)g,
        (__attribute__((address_space(3))) void*)l, 16, 0, 0);
}

// Split float4 into packed bf16 hi (RNE) and lo (RNE of exact residual).
__device__ __forceinline__ void split4(const float4 v, uint& h01, uint& h23,
                                       uint& l01, uint& l23) {
    const uint u0 = __float_as_uint(v.x) + 0x8000u;
    const uint u1 = __float_as_uint(v.y) + 0x8000u;
    const uint u2 = __float_as_uint(v.z) + 0x8000u;
    const uint u3 = __float_as_uint(v.w) + 0x8000u;
    h01 = __builtin_amdgcn_perm(u1, u0, 0x07060302u);
    h23 = __builtin_amdgcn_perm(u3, u2, 0x07060302u);
    const float f0 = v.x - __uint_as_float(u0 & 0xFFFF0000u);
    const float f1 = v.y - __uint_as_float(u1 & 0xFFFF0000u);
    const float f2 = v.z - __uint_as_float(u2 & 0xFFFF0000u);
    const float f3 = v.w - __uint_as_float(u3 & 0xFFFF0000u);
    l01 = __builtin_amdgcn_perm(__float_as_uint(f1) + 0x8000u,
                                __float_as_uint(f0) + 0x8000u, 0x07060302u);
    l23 = __builtin_amdgcn_perm(__float_as_uint(f3) + 0x8000u,
                                __float_as_uint(f2) + 0x8000u, 0x07060302u);
}

// ---- shared routing decision (identical in all paths; validated R5-R13) ----
template <class SC>
__device__ __forceinline__ bool route_core(SC sc, const float* __restrict__ bias,
                                           int* id, float* wv)
{
    float gs[NGROUP];
#pragma unroll
    for (int g = 0; g < NGROUP; ++g) {
        float m1 = -1e30f, m2 = -1e30f;
        for (int i = 0; i < GSIZE; ++i) {
            const int e = g * GSIZE + i;
            const float v = sc(e) + bias[e];
            if (v > m1)      { m2 = m1; m1 = v; }
            else if (v > m2) { m2 = v; }
        }
        gs[g] = m1 + m2;
    }

    unsigned gmask = 0;
    float g4 = -1e30f;
#pragma unroll
    for (int r = 0; r < TOPKG; ++r) {
        int bi = 0; float bv = -1e30f;
#pragma unroll
        for (int g = 0; g < NGROUP; ++g) {
            const bool taken = (gmask >> g) & 1;
            if (!taken && gs[g] > bv) { bv = gs[g]; bi = g; }
        }
        gmask |= 1u << bi;
        g4 = bv;
    }
    float g5 = -1e30f;
#pragma unroll
    for (int g = 0; g < NGROUP; ++g)
        if (!((gmask >> g) & 1) && gs[g] > g5) g5 = gs[g];

    float val[TOPK + 1]; int vid[TOPK + 1];
#pragma unroll
    for (int r = 0; r <= TOPK; ++r) { val[r] = -1e30f; vid[r] = 0; }
    for (int e = 0; e < NEXP; ++e) {
        const bool allowed = (gmask >> (e >> 5)) & 1;
        const float v = allowed ? (sc(e) + bias[e]) : 0.0f;
        if (v > val[TOPK]) {
#pragma unroll
            for (int p = TOPK; p >= 1; --p) {
                if (v > val[p - 1])  { val[p] = val[p - 1]; vid[p] = vid[p - 1]; }
                else if (v > val[p]) { val[p] = v;          vid[p] = e; }
            }
            if (v > val[0]) { val[0] = v; vid[0] = e; }
        }
    }

    bool tight = (g4 - g5 < TAUG);
#pragma unroll
    for (int i = 0; i < TOPK; ++i) tight |= (val[i] - val[i + 1] < TAU);

    float sum = 0.0f;
#pragma unroll
    for (int r = 0; r < TOPK; ++r) { id[r] = vid[r]; wv[r] = sc(vid[r]); sum += wv[r]; }
    const float inv = RSCALE / (sum + 1e-20f);
#pragma unroll
    for (int r = 0; r < TOPK; ++r) wv[r] *= inv;
    return tight;
}

// exact fp32 recompute + route for one token (cold fallback only)
__device__ void exact_token(const float* __restrict__ hs, const float* __restrict__ wt,
                            const float* __restrict__ bias, float* __restrict__ out, int t)
{
    float lg[NEXP];
    const float* hrow = hs + (size_t)t * HID;
    for (int e = 0; e < NEXP; ++e) {
        const float* wr = wt + (size_t)e * HID;
        float a = 0.0f;
        for (int k = 0; k < HID; k += 4) {
            const float4 x = *(const float4*)(hrow + k);
            const float4 b = *(const float4*)(wr + k);
            a = fmaf(x.x, b.x, a); a = fmaf(x.y, b.y, a);
            a = fmaf(x.z, b.z, a); a = fmaf(x.w, b.w, a);
        }
        lg[e] = 1.0f / (1.0f + expf(-a));
    }
    int id[TOPK]; float wv[TOPK];
    route_core([&](int e) { return lg[e]; }, bias, id, wv);
    for (int r = 0; r < TOPK; ++r) {
        out[(size_t)t * TOPK + r] = (float)id[r];
        out[(size_t)T_TOKENS * TOPK + (size_t)t * TOPK + r] = wv[r];
    }
}

// =============== one-shot weight conversion (R9-validated, unchanged) ===============
__global__ __launch_bounds__(256, 8)
void conv_weight(const float* __restrict__ wt, ushort* __restrict__ wq)
{
    const int g  = blockIdx.x * 256 + threadIdx.x;
    const int e  = g >> 9;
    const int kc = g & 511;
    const int sg  = kc >> 2;
    const int kch = kc & 3;

    const float4 v0 = *(const float4*)(wt + (size_t)e * HID + kc * 8);
    const float4 v1 = *(const float4*)(wt + (size_t)e * HID + kc * 8 + 4);
    uint h01, h23, l01, l23, h45, h67, l45, l67;
    split4(v0, h01, h23, l01, l23);
    split4(v1, h45, h67, l45, l67);

    const size_t idx = (size_t)sg * 8192 + (size_t)((e >> 4) * 512 + kch * 128 + (e & 15) * 8);
    uint4 hv; hv.x = h01; hv.y = h23; hv.z = h45; hv.w = h67;
    uint4 lv; lv.x = l01; lv.y = l23; lv.z = l45; lv.w = l67;
    *(uint4*)&wq[idx] = hv;
    *(uint4*)&wq[(size_t)WQ_LIMB + idx] = lv;
}

// =============== split-K GEMM v2 (R9-verbatim loop; XCD-local block swizzle) ===============
// block b -> (m, sk) s.t. an m-tile's 4 sk-slices land on the SAME XCD
// (dispatch round-robins consecutive blocks across 8 XCDs):
//   b = g*32 + s*8 + x  ->  m = g*8 + x, sk = s    (bijective, grid 1024)
__global__ __launch_bounds__(256, 4)
void router_gemm(const float* __restrict__ hs, const ushort* __restrict__ wq,
                 float* __restrict__ pw)
{
    __shared__ ushort u16[STG_TOT];

    const int tid  = threadIdx.x;
    const int lane = tid & 63;
    const int w    = tid >> 6;
    const int b    = blockIdx.x;
    const int m    = (b >> 5) * 8 + (b & 7);
    const int sk   = (b >> 3) & 3;
    const int t0   = m * BM;
    const int kb0  = sk * KSPAN;
    const int r0   = tid >> 3;           // 0..31
    const int q    = tid & 7;

    const ushort* wq_hi = wq;
    const ushort* wq_lo = wq + WQ_LIMB;

    f32x4 acc[4][4];
#pragma unroll
    for (int i = 0; i < 4; ++i)
#pragma unroll
        for (int j = 0; j < 4; ++j) acc[i][j] = (f32x4)0.0f;

    float4 ra[2];
#pragma unroll
    for (int s = 0; s < 2; ++s)
        ra[s] = *(const float4*)(hs + (size_t)(t0 + r0 + 32 * s) * HID + kb0 + q * 4);

    for (int ks = 0; ks < NKS; ++ks) {
        const int sg = sk * NKS + ks;
        __syncthreads();   // previous compute done; LDS reusable

        // ---- B: DMA pre-converted tiles (wave w stages its quarter) ----
        {
            const size_t gb = (size_t)sg * 8192 + (size_t)(w * 4) * 512 + (size_t)lane * 8;
#pragma unroll
            for (int i = 0; i < 4; ++i) {
                gload16(wq_hi + gb + i * 512, &u16[B_HI + (w * 4 + i) * 512]);
                gload16(wq_lo + gb + i * 512, &u16[B_LO + (w * 4 + i) * 512]);
            }
        }
        // ---- A: convert regs -> bf16 hi/lo, write frag-major LDS ----
#pragma unroll
        for (int s = 0; s < 2; ++s) {
            const int r = r0 + 32 * s;
            uint h01, h23, l01, l23;
            split4(ra[s], h01, h23, l01, l23);
            const int eo = stoffA(r, q);
            uint2 hv; hv.x = h01; hv.y = h23;
            uint2 lv; lv.x = l01; lv.y = l23;
            *(uint2*)&u16[A_HI + eo] = hv;
            *(uint2*)&u16[A_LO + eo] = lv;
        }
        __syncthreads();   // drains B DMA (vmcnt) + A writes visible

        // ---- prefetch next A K-step into regs ----
        if (ks + 1 < NKS) {
            const int kb = kb0 + (ks + 1) * BK;
#pragma unroll
            for (int s = 0; s < 2; ++s)
                ra[s] = *(const float4*)(hs + (size_t)(t0 + r0 + 32 * s) * HID + kb + q * 4);
        }

        // ---- compute: linear b128 frag reads (bank floor) + 48 MFMA/wave ----
        const int fo = froffL(lane);
        bf16x8 ah[4], al[4];
#pragma unroll
        for (int rt = 0; rt < 4; ++rt) {
            ah[rt] = *(const bf16x8*)&u16[A_HI + rt * 512 + fo];
            al[rt] = *(const bf16x8*)&u16[A_LO + rt * 512 + fo];
        }
#pragma unroll
        for (int c = 0; c < 4; ++c) {
            const int ct = w * 4 + c;
            const bf16x8 bh = *(const bf16x8*)&u16[B_HI + ct * 512 + fo];
            const bf16x8 bl = *(const bf16x8*)&u16[B_LO + ct * 512 + fo];
#pragma unroll
            for (int rt = 0; rt < 4; ++rt) {
                acc[rt][c] = __builtin_amdgcn_mfma_f32_16x16x32_bf16(ah[rt], bh, acc[rt][c], 0, 0, 0);
                acc[rt][c] = __builtin_amdgcn_mfma_f32_16x16x32_bf16(ah[rt], bl, acc[rt][c], 0, 0, 0);
                acc[rt][c] = __builtin_amdgcn_mfma_f32_16x16x32_bf16(al[rt], bh, acc[rt][c], 0, 0, 0);
            }
        }
    }

    // ---- store raw partial logits: pw[sk][token][expert] ----
#pragma unroll
    for (int rt = 0; rt < 4; ++rt)
#pragma unroll
        for (int c = 0; c < 4; ++c) {
            const int col  = w * 64 + c * 16 + (lane & 15);
            const int rowb = rt * 16 + (lane >> 4) * 4;
#pragma unroll
            for (int j = 0; j < 4; ++j)
                pw[((size_t)(sk * T_TOKENS) + t0 + rowb + j) * NEXP + col] = acc[rt][c][j];
        }
}

// =============== routing v2: 16 tokens/block, grid 1024 (4 blocks/CU) ===============
// block b_r -> m with m%8 == b_r%8 (same XCD as the gemm blocks that wrote pw[m])
__global__ __launch_bounds__(256, 4)
void router_route(const float* __restrict__ pw, const float* __restrict__ bias,
                  float* __restrict__ out,
                  unsigned* __restrict__ wcnt, unsigned* __restrict__ wlist,
                  unsigned cap)
{
    __shared__ float Lg[NEXP * RT_TOK];  // 16 KB
    const int tid  = threadIdx.x;
    const int b    = blockIdx.x;         // 1024
    const int x    = b & 7;
    const int rest = b >> 3;             // 0..127
    const int m    = (rest >> 2) * 8 + x;
    const int sub  = rest & 3;
    const int t0   = m * BM + sub * RT_TOK;

#pragma unroll
    for (int t = 0; t < RT_TOK; ++t) {
        float v = 0.0f;
#pragma unroll
        for (int s = 0; s < SPLITK; ++s)
            v += pw[((size_t)(s * T_TOKENS) + t0 + t) * NEXP + tid];
        Lg[tid * RT_TOK + ((t + tid) & (RT_TOK - 1))] = 1.0f / (1.0f + expf(-v));
    }
    __syncthreads();

    if (tid < RT_TOK) {
        const int t = t0 + tid;
        int id[TOPK]; float wv[TOPK];
        const bool tight = route_core(
            [&](int e) { return Lg[e * RT_TOK + ((tid + e) & (RT_TOK - 1))]; },
            bias, id, wv);

#pragma unroll
        for (int r = 0; r < TOPK; ++r) {
            out[(size_t)t * TOPK + r] = (float)id[r];
            out[(size_t)T_TOKENS * TOPK + (size_t)t * TOPK + r] = wv[r];
        }
        if (tight) {
            const unsigned pos = atomicAdd(wcnt, 1u);
            if (pos < cap) wlist[pos] = (unsigned)t;
        }
    }
}

// =============== cleanup v3 (R8-verbatim): one token per block, deep-issue ===============
__global__ __launch_bounds__(256, 4)
void router_exact(const float* __restrict__ hs, const float* __restrict__ wt,
                  const float* __restrict__ bias, float* __restrict__ out,
                  const unsigned* __restrict__ wcnt, const unsigned* __restrict__ wlist,
                  unsigned cap)
{
    __shared__ float hrow[HID];          // 16 KB
    __shared__ float lg[NEXP];           // 1 KB
    const unsigned count = min(*wcnt, cap);
    const int tid  = threadIdx.x;
    const int lane = tid & 63;
    const int w    = tid >> 6;

    for (unsigned b = blockIdx.x; b < count; b += gridDim.x) {
        __syncthreads();                 // guard hrow/lg reuse across passes
        const int t = (int)wlist[b];

#pragma unroll
        for (int i = 0; i < 4; ++i) {
            const int f4 = i * 256 + tid;
            *(float4*)&hrow[f4 * 4] = *(const float4*)(hs + (size_t)t * HID + f4 * 4);
        }
        __syncthreads();

        for (int g = 0; g < 16; ++g) {
            const int e0 = w * 64 + g * 4;
            float a[4] = {0.0f, 0.0f, 0.0f, 0.0f};
#pragma unroll 4
            for (int j = 0; j < 16; ++j) {
                const int f4 = j * 64 + lane;
                const float4 h = *(const float4*)&hrow[f4 * 4];
#pragma unroll
                for (int p = 0; p < 4; ++p) {
                    const float4 v = *(const float4*)(wt + (size_t)(e0 + p) * HID + f4 * 4);
                    a[p] = fmaf(h.x, v.x, a[p]); a[p] = fmaf(h.y, v.y, a[p]);
                    a[p] = fmaf(h.z, v.z, a[p]); a[p] = fmaf(h.w, v.w, a[p]);
                }
            }
#pragma unroll
            for (int p = 0; p < 4; ++p)
#pragma unroll
                for (int d = 1; d < 64; d <<= 1)
                    a[p] += __shfl_xor(a[p], d, 64);
            if (lane == 0) {
#pragma unroll
                for (int p = 0; p < 4; ++p)
                    lg[e0 + p] = 1.0f / (1.0f + expf(-a[p]));
            }
        }
        __syncthreads();

        if (tid == 0) {
            int id[TOPK]; float wv[TOPK];
            route_core([&](int e) { return lg[e]; }, bias, id, wv);
            for (int r = 0; r < TOPK; ++r) {
                out[(size_t)t * TOPK + r] = (float)id[r];
                out[(size_t)T_TOKENS * TOPK + (size_t)t * TOPK + r] = wv[r];
            }
        }
    }
}

// =============== fallback monolith (R5-validated, unchanged) ===============
__global__ __launch_bounds__(512, 1)
void router_mono(const float* __restrict__ hs, const float* __restrict__ wt,
                 const float* __restrict__ bias, float* __restrict__ out,
                 unsigned* __restrict__ wcnt, unsigned* __restrict__ wlist, unsigned cap)
{
    __shared__ float smem[16384];
    ushort* u16 = (ushort*)smem;
    float*  Lg  = smem;

    const int tid  = threadIdx.x;
    const int lane = tid & 63;
    const int w    = tid >> 6;
    const int t0   = blockIdx.x * 64;
    const int ar   = tid >> 3;
    const int aq   = tid & 7;

    f32x4 acc[4][2];
#pragma unroll
    for (int i = 0; i < 4; ++i)
#pragma unroll
        for (int j = 0; j < 2; ++j) acc[i][j] = (f32x4)0.0f;

    float4 ra, rb[4];
    ra = *(const float4*)(hs + (size_t)(t0 + ar) * HID + aq * 4);
#pragma unroll
    for (int s = 0; s < 4; ++s)
        rb[s] = *(const float4*)(wt + (size_t)(ar + s * 64) * HID + aq * 4);

    for (int ks = 0; ks < HID / BK; ++ks) {
        __syncthreads();
        {
            uint h01, h23, l01, l23;
            split4(ra, h01, h23, l01, l23);
            const int eo = stoffA(ar, aq);
            uint2 hv; hv.x = h01; hv.y = h23;
            uint2 lv; lv.x = l01; lv.y = l23;
            *(uint2*)&u16[0 + eo] = hv;
            *(uint2*)&u16[2048 + eo] = lv;
        }
#pragma unroll
        for (int s = 0; s < 4; ++s) {
            const int e = ar + s * 64;
            uint h01, h23, l01, l23;
            split4(rb[s], h01, h23, l01, l23);
            const int eo = stoffA(e, aq);
            uint2 hv; hv.x = h01; hv.y = h23;
            uint2 lv; lv.x = l01; lv.y = l23;
            *(uint2*)&u16[4096 + eo] = hv;
            *(uint2*)&u16[12288 + eo] = lv;
        }
        __syncthreads();
        if (ks + 1 < HID / BK) {
            const int k0 = (ks + 1) * BK;
            ra = *(const float4*)(hs + (size_t)(t0 + ar) * HID + k0 + aq * 4);
#pragma unroll
            for (int s = 0; s < 4; ++s)
                rb[s] = *(const float4*)(wt + (size_t)(ar + s * 64) * HID + k0 + aq * 4);
        }
        const int fo = froffL(lane);
        bf16x8 ah[4], al[4];
#pragma unroll
        for (int rt = 0; rt < 4; ++rt) {
            ah[rt] = *(const bf16x8*)&u16[0 + rt * 512 + fo];
            al[rt] = *(const bf16x8*)&u16[2048 + rt * 512 + fo];
        }
#pragma unroll
        for (int c = 0; c < 2; ++c) {
            const int ct = w * 2 + c;
            const bf16x8 bh = *(const bf16x8*)&u16[4096 + ct * 512 + fo];
            const bf16x8 bl = *(const bf16x8*)&u16[12288 + ct * 512 + fo];
#pragma unroll
            for (int rt = 0; rt < 4; ++rt) {
                acc[rt][c] = __builtin_amdgcn_mfma_f32_16x16x32_bf16(ah[rt], bh, acc[rt][c], 0, 0, 0);
                acc[rt][c] = __builtin_amdgcn_mfma_f32_16x16x32_bf16(ah[rt], bl, acc[rt][c], 0, 0, 0);
                acc[rt][c] = __builtin_amdgcn_mfma_f32_16x16x32_bf16(al[rt], bh, acc[rt][c], 0, 0, 0);
            }
        }
    }
    __syncthreads();
#pragma unroll
    for (int rt = 0; rt < 4; ++rt)
#pragma unroll
        for (int c = 0; c < 2; ++c) {
            const int col  = w * 32 + c * 16 + (lane & 15);
            const int rowb = rt * 16 + (lane >> 4) * 4;
#pragma unroll
            for (int j = 0; j < 4; ++j) {
                const int row = rowb + j;
                Lg[col * 64 + ((row + col) & 63)] = 1.0f / (1.0f + expf(-acc[rt][c][j]));
            }
        }
    __syncthreads();

    if (tid < 64) {
        const int t = t0 + tid;
        int id[TOPK]; float wv[TOPK];
        const bool tight = route_core(
            [&](int e) { return Lg[e * 64 + ((tid + e) & 63)]; }, bias, id, wv);
#pragma unroll
        for (int r = 0; r < TOPK; ++r) {
            out[(size_t)t * TOPK + r] = (float)id[r];
            out[(size_t)T_TOKENS * TOPK + (size_t)t * TOPK + r] = wv[r];
        }
        if (tight) {
            bool queued = false;
            if (wcnt) {
                const unsigned pos = atomicAdd(wcnt, 1u);
                if (pos < cap) { wlist[pos] = (unsigned)t; queued = true; }
            }
            if (!queued) exact_token(hs, wt, bias, out, t);
        }
    }
}

extern "C" void kernel_launch(void* const* d_in, const int* in_sizes, int n_in,
                              void* d_out, int out_size, void* d_ws, size_t ws_size,
                              hipStream_t stream) {
    const float* hs   = (const float*)d_in[0];   // [16384, 4096] f32
    const float* wt   = (const float*)d_in[1];   // [256, 4096]   f32
    const float* bias = (const float*)d_in[2];   // [256]         f32
    float* out = (float*)d_out;
    (void)in_sizes; (void)n_in; (void)out_size;

    const size_t PW_BYTES = (size_t)SPLITK * T_TOKENS * NEXP * 4;   // 64 MB
    const size_t WQ_BYTES = (size_t)2 * WQ_LIMB * 2;                // 4 MB
    const size_t NEED = PW_BYTES + WQ_BYTES + 4 + (size_t)T_TOKENS * 4;

    if (ws_size >= NEED) {
        float*    pw    = (float*)d_ws;
        ushort*   wq    = (ushort*)((char*)d_ws + PW_BYTES);
        unsigned* wcnt  = (unsigned*)((char*)d_ws + PW_BYTES + WQ_BYTES);
        unsigned* wlist = wcnt + 1;
        hipMemsetAsync(wcnt, 0, sizeof(unsigned), stream);
        conv_weight<<<512, 256, 0, stream>>>(wt, wq);
        router_gemm<<<(T_TOKENS / BM) * SPLITK, 256, 0, stream>>>(hs, wq, pw);
        router_route<<<T_TOKENS / RT_TOK, 256, 0, stream>>>(pw, bias, out, wcnt, wlist,
                                                            (unsigned)T_TOKENS);
        router_exact<<<2048, 256, 0, stream>>>(hs, wt, bias, out, wcnt, wlist,
                                               (unsigned)T_TOKENS);
    } else if (ws_size >= 8) {
        unsigned cap = (unsigned)((ws_size - 4) / 4);
        if (cap > T_TOKENS) cap = T_TOKENS;
        unsigned* wcnt  = (unsigned*)d_ws;
        unsigned* wlist = wcnt + 1;
        hipMemsetAsync(d_ws, 0, sizeof(unsigned), stream);
        router_mono<<<T_TOKENS / 64, 512, 0, stream>>>(hs, wt, bias, out, wcnt, wlist, cap);
        router_exact<<<2048, 256, 0, stream>>>(hs, wt, bias, out, wcnt, wlist, cap);
    } else {
        router_mono<<<T_TOKENS / 64, 512, 0, stream>>>(hs, wt, bias, out,
                                                       nullptr, nullptr, 0u);
    }
}